// Round 3
// baseline (6838.883 us; speedup 1.0000x reference)
//
#include <hip/hip_runtime.h>
#include <cstdint>
#include <cstddef>

// ============================================================================
// LSTMClassifierQuantized: B=64, S=512, H=E=512, 4H=2048, per-tensor int8
// fake-quant on x_t/h/c/W per step. Sequential over 512 steps, one grid
// barrier per step (global max|h|, max|c| scales force it).
//
// R3 vs R2:
//  - 32 blocks x 512 thr (was 64x256): halves h fan-out (4 MB/step), each
//    block owns 16 hidden units / 64 gate cols. 1 block/CU, 8 waves.
//  - contention-free barrier: NO atomic RMWs. Block bk stores {MH,MC} into
//    rec ring slot [t+1 mod 4][bk], vmcnt-drains, then stores flag[bk]=t+1.
//    Wave0 lanes 0..31 poll the 32 flags in parallel (__all ballot), then
//    read the 32 recs and shfl-reduce max -> global scales. Scale broadcast
//    is merged into the barrier (removes the old sloth/slotc RMW lines).
//  - x A-fragments loaded before the spin (no barrier dependency): latency
//    hides under barrier wait.
//  - h exchange stays 8B agent-relaxed atomics (R2-validated coherent).
// ============================================================================

typedef int v4i __attribute__((ext_vector_type(4)));

#define NB   64
#define SEQ  512
#define HID  512
#define G4   2048
#define NBLK 32
#define NTHR 512

// workspace byte offsets
#define OFF_FLAG    0             // u32[32] per-block progress flags
#define OFF_FREC    128           // u32[32] final capmax records
#define OFF_SLOT1   256           // u32[4]: wi, wh, lw abs-max bits
#define OFF_SX      320           // f32[512] raw max|x_t|
#define OFF_LEN     2368          // i32[64]
#define OFF_REC     2688          // u64[4][32] {MH,MC} ring (skew <= 1 step)
#define OFF_HG      3712          // f32[2][64*512] double-buffered h row-major
#define ZERO_BYTES  265856
#define OFF_HLAST   265856        // f32[64*512] row-major
#define OFF_WIF     396928        // v4i[65536] frag-major int8 Wi (1 MB)
#define OFF_WHF     1445504       // v4i[65536]
#define OFF_XF      2494080       // v4i[512*2048] frag-major int8 x (16 MB)
#define WS_NEED     19271296

#define ATOMIC_LD(p)    __hip_atomic_load((p), __ATOMIC_RELAXED, __HIP_MEMORY_SCOPE_AGENT)
#define ATOMIC_ST(p, v) __hip_atomic_store((p), (v), __ATOMIC_RELAXED, __HIP_MEMORY_SCOPE_AGENT)

__device__ __forceinline__ int fragidx(int row, int kq) {
  // 16-byte chunk index for A-operand fragment: lane l of tile (m,kb) holds
  // A[row=m*16+(l&15)][k=kb*64+(l>>4)*16 + 0..15]
  return ((row >> 4) * 8 + (kq >> 2)) * 64 + ((kq & 3) << 4) + (row & 15);
}

__device__ __forceinline__ float sigm(float x) {
  return 1.0f / (1.0f + __expf(-x));
}

// magic-number round-to-nearest-even int8 pack of 2 floats (|x*inv| <= 127)
__device__ __forceinline__ unsigned pack2(unsigned long long v, float inv) {
  union { unsigned long long u; float f[2]; } q; q.u = v;
  union { float f; unsigned u; } a, b;
  a.f = __builtin_fmaf(q.f[0], inv, 12582912.0f);   // 1.5 * 2^23
  b.f = __builtin_fmaf(q.f[1], inv, 12582912.0f);
  return (a.u & 0xffu) | ((b.u & 0xffu) << 8);
}

// exact-IEEE-division quantize pack (setup kernels)
__device__ __forceinline__ unsigned packdiv(const float* p, float s) {
  unsigned r = 0;
#pragma unroll
  for (int j = 0; j < 4; j++) {
    int n = (int)rintf(p[j] / s);
    r |= ((unsigned)n & 0xffu) << (8 * j);
  }
  return r;
}

// ------------------------------- setup kernels ------------------------------

__global__ void k_maxw(const float* __restrict__ wi, const float* __restrict__ wh,
                       const float* __restrict__ lw, unsigned* ws_u) {
  float m1 = 0.f, m2 = 0.f, m3 = 0.f;
  int stride = gridDim.x * blockDim.x;
  int t0 = blockIdx.x * blockDim.x + threadIdx.x;
  for (int i = t0; i < G4 * HID; i += stride) m1 = fmaxf(m1, fabsf(wi[i]));
  for (int i = t0; i < G4 * HID; i += stride) m2 = fmaxf(m2, fabsf(wh[i]));
  for (int i = t0; i < HID; i += stride)      m3 = fmaxf(m3, fabsf(lw[i]));
#pragma unroll
  for (int o = 32; o > 0; o >>= 1) {
    m1 = fmaxf(m1, __shfl_down(m1, o));
    m2 = fmaxf(m2, __shfl_down(m2, o));
    m3 = fmaxf(m3, __shfl_down(m3, o));
  }
  __shared__ float s1[4], s2[4], s3[4];
  int w = threadIdx.x >> 6, l = threadIdx.x & 63;
  if (l == 0) { s1[w] = m1; s2[w] = m2; s3[w] = m3; }
  __syncthreads();
  if (threadIdx.x == 0) {
    m1 = fmaxf(fmaxf(s1[0], s1[1]), fmaxf(s1[2], s1[3]));
    m2 = fmaxf(fmaxf(s2[0], s2[1]), fmaxf(s2[2], s2[3]));
    m3 = fmaxf(fmaxf(s3[0], s3[1]), fmaxf(s3[2], s3[3]));
    atomicMax(&ws_u[OFF_SLOT1 / 4 + 0], __float_as_uint(m1));
    atomicMax(&ws_u[OFF_SLOT1 / 4 + 1], __float_as_uint(m2));
    atomicMax(&ws_u[OFF_SLOT1 / 4 + 2], __float_as_uint(m3));
  }
}

__global__ void k_sx(const int* __restrict__ ids, const float* __restrict__ emb,
                     float* sx) {
  int t = blockIdx.x, tid = threadIdx.x;
  int row = tid >> 2, qu = tid & 3;
  const float* e = emb + (size_t)ids[row * SEQ + t] * HID + qu * 128;
  float m = 0.f;
  for (int i = 0; i < 128; i++) m = fmaxf(m, fabsf(e[i]));
#pragma unroll
  for (int o = 32; o > 0; o >>= 1) m = fmaxf(m, __shfl_down(m, o));
  __shared__ float sm[4];
  if ((tid & 63) == 0) sm[tid >> 6] = m;
  __syncthreads();
  if (tid == 0) sx[t] = fmaxf(fmaxf(sm[0], sm[1]), fmaxf(sm[2], sm[3]));
}

__global__ void k_len(const int* __restrict__ mask, int* len) {
  int b = threadIdx.x;
  int s = 0;
  for (int i = 0; i < SEQ; i++) s += mask[b * SEQ + i];
  len[b] = (s + SEQ - 1) & (SEQ - 1);   // (sum-1) mod 512, jnp wrap semantics
}

// Weight fragments for 32-block geometry: wf[bk(32)][ct(4)][kb(8)][lane(64)].
// Column mapping: gate g = ct, unit = bk*16 + cc -> global col = ct*512+bk*16+cc.
__global__ void k_wf(const float* __restrict__ wi, const float* __restrict__ wh,
                     const unsigned* ws_u, v4i* wif, v4i* whf) {
  int t = blockIdx.x * 256 + threadIdx.x;          // 0..65535
  int lane = t & 63, kb = (t >> 6) & 7, ct = (t >> 9) & 3, bk = t >> 11;
  int cc = lane & 15, q = lane >> 4;
  int col = ct * 512 + bk * 16 + cc;
  int k0 = kb * 64 + q * 16;
  float si = fmaxf(__uint_as_float(ws_u[OFF_SLOT1 / 4 + 0]), 1e-8f) / 127.0f;
  float sh = fmaxf(__uint_as_float(ws_u[OFF_SLOT1 / 4 + 1]), 1e-8f) / 127.0f;
  float buf[16];
#pragma unroll
  for (int j = 0; j < 16; j++) buf[j] = wi[(size_t)col * 512 + k0 + j];
  v4i o;
  o[0] = (int)packdiv(buf + 0, si);  o[1] = (int)packdiv(buf + 4, si);
  o[2] = (int)packdiv(buf + 8, si);  o[3] = (int)packdiv(buf + 12, si);
  wif[t] = o;
#pragma unroll
  for (int j = 0; j < 16; j++) buf[j] = wh[(size_t)col * 512 + k0 + j];
  o[0] = (int)packdiv(buf + 0, sh);  o[1] = (int)packdiv(buf + 4, sh);
  o[2] = (int)packdiv(buf + 8, sh);  o[3] = (int)packdiv(buf + 12, sh);
  whf[t] = o;
}

__global__ void k_xf(const int* __restrict__ ids, const float* __restrict__ emb,
                     const float* __restrict__ sx, v4i* xf) {
  int g = blockIdx.x * 256 + threadIdx.x;          // 0..1048575 == t*2048+idx
  int t = g >> 11, idx = g & 2047;
  int r = idx & 15, q = (idx >> 4) & 3, kb = (idx >> 6) & 7, m = idx >> 9;
  int row = m * 16 + r;
  int k0 = ((kb << 2) + q) << 4;
  float s = fmaxf(sx[t], 1e-8f) / 127.0f;
  const float* e = emb + (size_t)ids[row * SEQ + t] * HID + k0;
  float buf[16];
#pragma unroll
  for (int j = 0; j < 16; j++) buf[j] = e[j];
  v4i o;
  o[0] = (int)packdiv(buf + 0, s);  o[1] = (int)packdiv(buf + 4, s);
  o[2] = (int)packdiv(buf + 8, s);  o[3] = (int)packdiv(buf + 12, s);
  xf[g] = o;
}

// ------------------------------ persistent kernel ---------------------------

__global__ __launch_bounds__(NTHR, 2) void k_main(
    char* ws, const float* __restrict__ b_inp, const float* __restrict__ b_hid,
    const float* __restrict__ lin_w, const float* __restrict__ lin_b,
    float* __restrict__ out) {
  const int tid  = threadIdx.x;
  const int bk   = blockIdx.x;
  const int lane = tid & 63;
  const int wv   = tid >> 6;               // 8 waves
  const int cc   = lane & 15, qq = lane >> 4;
  const int ct   = wv >> 1;                // gate / col-tile (4 tiles of 16)
  const int bsel = wv & 1;
  const int rt0  = bsel, rt1 = bsel + 2;   // 2 row-tiles per wave

  unsigned* flag  = (unsigned*)(ws + OFF_FLAG);
  unsigned* frec  = (unsigned*)(ws + OFF_FREC);
  unsigned* slot1 = (unsigned*)(ws + OFF_SLOT1);
  const float* sxr = (const float*)(ws + OFF_SX);
  const int* lens  = (const int*)(ws + OFF_LEN);
  unsigned long long* rec = (unsigned long long*)(ws + OFF_REC);
  float* hg    = (float*)(ws + OFF_HG);
  float* hlast = (float*)(ws + OFF_HLAST);
  const v4i* wifg = (const v4i*)(ws + OFF_WIF);
  const v4i* whfg = (const v4i*)(ws + OFF_WHF);
  const v4i* xfg  = (const v4i*)(ws + OFF_XF);

  __shared__ v4i hfrag[2048];        // 32 KB int8 h fragments
  __shared__ float gl[64][65];       // gates [row][ct*16+u], +1 pad
  __shared__ float redh[8], redc[8], sml[2];

  // weight fragments -> VGPRs for the whole kernel (1 col-tile x 2 matrices)
  v4i wif[8], whf[8];
  {
    int base = ((bk * 4 + ct) * 8) * 64 + lane;
#pragma unroll
    for (int kb = 0; kb < 8; kb++) {
      wif[kb] = wifg[base + kb * 64];
      whf[kb] = whfg[base + kb * 64];
    }
  }
  const int colg = ct * 512 + bk * 16 + cc;
  const float bi = b_inp[colg], bh = b_hid[colg];
  const float swi = fmaxf(__uint_as_float(slot1[0]), 1e-8f) / 127.0f;
  const float swh = fmaxf(__uint_as_float(slot1[1]), 1e-8f) / 127.0f;

  // elementwise cell ownership: thread -> (row, 2 adjacent units of this block)
  const int erow = tid >> 3;               // 0..63
  const int eu   = (tid & 7) * 2;          // 0,2,..,14 (local unit)
  const int hcol = bk * 16 + eu;           // global unit (8B aligned pair)
  const int mylen = lens[erow];
  float c0 = 0.0f, c1 = 0.0f, capmax = 0.0f;

  // consumer mapping: thread reads 64 consecutive h floats of one row
  const int crow = tid >> 3, cseg = tid & 7;
  const int cbase = crow * 512 + cseg * 64;

  for (int t = 0; t < SEQ; ++t) {
    const v4i* xt = xfg + t * 2048;

    // x A-fragments: no barrier dependency -> issue before the spin
    v4i xa0[8], xa1[8];
#pragma unroll
    for (int kb = 0; kb < 8; kb++) {
      xa0[kb] = xt[(rt0 * 8 + kb) * 64 + lane];
      xa1[kb] = xt[(rt1 * 8 + kb) * 64 + lane];
    }

    // ---- grid barrier + scale gather (wave0) ----
    if (wv == 0) {
      const unsigned ut = (unsigned)t;
      const bool act = lane < NBLK;
      for (;;) {
        unsigned f = act ? ATOMIC_LD(&flag[lane]) : 0xffffffffu;
        if (__all((int)(f >= ut))) break;
      }
      unsigned long long rv = act ? ATOMIC_LD(&rec[(t & 3) * NBLK + lane]) : 0ull;
      float mh = __uint_as_float((unsigned)rv);
      float mc = __uint_as_float((unsigned)(rv >> 32));
#pragma unroll
      for (int o = 32; o > 0; o >>= 1) {
        mh = fmaxf(mh, __shfl_xor(mh, o));
        mc = fmaxf(mc, __shfl_xor(mc, o));
      }
      if (lane == 0) { sml[0] = mh; sml[1] = mc; }
    }
    __syncthreads();   // (A) scales ready; h from step t-1 globally visible

    const float th   = fmaxf(sml[0], 1e-8f);
    const float shq  = th / 127.0f;
    const float invh = 127.0f / th;
    const float tc   = fmaxf(sml[1], 1e-8f);
    const float scq  = tc / 127.0f;
    const float invc = 127.0f / tc;
    const float fx = (fmaxf(sxr[t], 1e-8f) / 127.0f) * swi;
    const float fh = shq * swh;

    const float* hr = hg + (t & 1) * (NB * HID);
    float*       hw = hg + ((t + 1) & 1) * (NB * HID);

    // ---- h: coherence-point loads -> int8 pack -> frag-major LDS ----
    {
      const unsigned long long* hp = (const unsigned long long*)(hr + cbase);
#pragma unroll
      for (int ii = 0; ii < 4; ii++) {
        unsigned long long d0 = ATOMIC_LD(hp + ii * 8 + 0);
        unsigned long long d1 = ATOMIC_LD(hp + ii * 8 + 1);
        unsigned long long d2 = ATOMIC_LD(hp + ii * 8 + 2);
        unsigned long long d3 = ATOMIC_LD(hp + ii * 8 + 3);
        unsigned long long d4 = ATOMIC_LD(hp + ii * 8 + 4);
        unsigned long long d5 = ATOMIC_LD(hp + ii * 8 + 5);
        unsigned long long d6 = ATOMIC_LD(hp + ii * 8 + 6);
        unsigned long long d7 = ATOMIC_LD(hp + ii * 8 + 7);
        v4i pk;
        pk[0] = (int)(pack2(d0, invh) | (pack2(d1, invh) << 16));
        pk[1] = (int)(pack2(d2, invh) | (pack2(d3, invh) << 16));
        pk[2] = (int)(pack2(d4, invh) | (pack2(d5, invh) << 16));
        pk[3] = (int)(pack2(d6, invh) | (pack2(d7, invh) << 16));
        hfrag[fragidx(crow, cseg * 4 + ii)] = pk;
      }
    }
    __syncthreads();   // (B) hfrag ready

    // ---- GEMM: exact int8 MFMA, separate x/h accumulators ----
    v4i ax0 = {0, 0, 0, 0}, ax1 = {0, 0, 0, 0};
    v4i ah0 = {0, 0, 0, 0}, ah1 = {0, 0, 0, 0};
#pragma unroll
    for (int kb = 0; kb < 8; kb++) {
      v4i h0 = hfrag[(rt0 * 8 + kb) * 64 + lane];
      v4i h1 = hfrag[(rt1 * 8 + kb) * 64 + lane];
      ax0 = __builtin_amdgcn_mfma_i32_16x16x64_i8(xa0[kb], wif[kb], ax0, 0, 0, 0);
      ah0 = __builtin_amdgcn_mfma_i32_16x16x64_i8(h0,      whf[kb], ah0, 0, 0, 0);
      ax1 = __builtin_amdgcn_mfma_i32_16x16x64_i8(xa1[kb], wif[kb], ax1, 0, 0, 0);
      ah1 = __builtin_amdgcn_mfma_i32_16x16x64_i8(h1,      whf[kb], ah1, 0, 0, 0);
    }
    // epilogue: mirror np order ((x@WiT + b_inp) + h@WhT) + b_hid
#pragma unroll
    for (int r = 0; r < 4; r++) {
      int r0 = rt0 * 16 + qq * 4 + r;
      int r1 = rt1 * 16 + qq * 4 + r;
      gl[r0][ct * 16 + cc] = (((float)ax0[r] * fx + bi) + (float)ah0[r] * fh) + bh;
      gl[r1][ct * 16 + cc] = (((float)ax1[r] * fx + bi) + (float)ah1[r] * fh) + bh;
    }
    __syncthreads();   // (C) gates ready

    // ---- elementwise LSTM cell update (2 cells/thread, c in registers) ----
    float i0 = sigm(gl[erow][eu]);
    float i1 = sigm(gl[erow][eu + 1]);
    float f0 = sigm(gl[erow][16 + eu]);
    float f1 = sigm(gl[erow][16 + eu + 1]);
    float g0 = tanhf(gl[erow][32 + eu]);
    float g1 = tanhf(gl[erow][32 + eu + 1]);
    float o0 = sigm(gl[erow][48 + eu]);
    float o1 = sigm(gl[erow][48 + eu + 1]);
    float cq0 = rintf(c0 * invc) * scq;
    float cq1 = rintf(c1 * invc) * scq;
    float cn0 = f0 * cq0 + i0 * g0;
    float cn1 = f1 * cq1 + i1 * g1;
    float hn0 = o0 * tanhf(cn0);
    float hn1 = o1 * tanhf(cn1);
    c0 = cn0; c1 = cn1;

    // publish h (coherence point, 8B)
    union { float f[2]; unsigned long long u; } hu;
    hu.f[0] = hn0; hu.f[1] = hn1;
    ATOMIC_ST((unsigned long long*)(hw + erow * 512 + hcol), hu.u);
    if (t == mylen) {
      ATOMIC_ST((unsigned long long*)(hlast + erow * 512 + hcol), hu.u);
      capmax = fmaxf(capmax, fmaxf(fabsf(hn0), fabsf(hn1)));
    }

    // block abs-max of new h and c
    float mhv = fmaxf(fabsf(hn0), fabsf(hn1));
    float mcv = fmaxf(fabsf(cn0), fabsf(cn1));
#pragma unroll
    for (int o = 32; o > 0; o >>= 1) {
      mhv = fmaxf(mhv, __shfl_xor(mhv, o));
      mcv = fmaxf(mcv, __shfl_xor(mcv, o));
    }
    if (lane == 0) { redh[wv] = mhv; redc[wv] = mcv; }
    __syncthreads();   // (D) all h stores drained (vmcnt0 at barrier), reds ready

    if (wv == 0 && lane == 0) {
      float MH = redh[0], MC = redc[0];
#pragma unroll
      for (int i = 1; i < 8; i++) {
        MH = fmaxf(MH, redh[i]);
        MC = fmaxf(MC, redc[i]);
      }
      unsigned long long rv = (unsigned long long)__float_as_uint(MH) |
                              ((unsigned long long)__float_as_uint(MC) << 32);
      ATOMIC_ST(&rec[((t + 1) & 3) * NBLK + bk], rv);
      asm volatile("s_waitcnt vmcnt(0)" ::: "memory");  // rec visible first
      ATOMIC_ST(&flag[bk], (unsigned)(t + 1));
    }
  }

  // ---- final round: capture max, then block 0 computes logits ----
#pragma unroll
  for (int o = 32; o > 0; o >>= 1)
    capmax = fmaxf(capmax, __shfl_xor(capmax, o));
  if (lane == 0) redh[wv] = capmax;
  __syncthreads();
  if (wv == 0 && lane == 0) {
    float CM = redh[0];
#pragma unroll
    for (int i = 1; i < 8; i++) CM = fmaxf(CM, redh[i]);
    ATOMIC_ST(&frec[bk], __float_as_uint(CM));
    asm volatile("s_waitcnt vmcnt(0)" ::: "memory");   // frec + hlast visible
    ATOMIC_ST(&flag[bk], (unsigned)(SEQ + 1));
  }
  if (bk != 0) return;

  if (wv == 0) {
    const bool act = lane < NBLK;
    for (;;) {
      unsigned f = act ? ATOMIC_LD(&flag[lane]) : 0xffffffffu;
      if (__all((int)(f >= (unsigned)(SEQ + 1)))) break;
    }
    unsigned fv = act ? ATOMIC_LD(&frec[lane]) : 0u;
    float cm = __uint_as_float(fv);
#pragma unroll
    for (int o = 32; o > 0; o >>= 1) cm = fmaxf(cm, __shfl_xor(cm, o));
    if (lane == 0) sml[0] = cm;
  }
  __syncthreads();

  {
    float tHL = fmaxf(sml[0], 1e-8f);
    float sHL = tHL / 127.0f, invHL = 127.0f / tHL;
    float tLW = fmaxf(__uint_as_float(slot1[2]), 1e-8f);
    float sLW = tLW / 127.0f, invLW = 127.0f / tLW;
    const unsigned long long* hp =
        (const unsigned long long*)(hlast + crow * 512 + cseg * 64);
    float acc = 0.0f;
    for (int j = 0; j < 32; ++j) {
      union { unsigned long long u; float f[2]; } d;
      d.u = ATOMIC_LD(hp + j);
      float hq0 = rintf(d.f[0] * invHL) * sHL;
      float wq0 = rintf(lin_w[cseg * 64 + 2 * j] * invLW) * sLW;
      acc += hq0 * wq0;
      float hq1 = rintf(d.f[1] * invHL) * sHL;
      float wq1 = rintf(lin_w[cseg * 64 + 2 * j + 1] * invLW) * sLW;
      acc += hq1 * wq1;
    }
    float* fl = &gl[0][0];
    fl[tid] = acc;                 // tid = row*8 + seg
    __syncthreads();
    if (tid < 64) {
      float s = 0.0f;
#pragma unroll
      for (int k = 0; k < 8; k++) s += fl[tid * 8 + k];
      out[tid] = s + lin_b[0];
    }
  }
}

// --------------------------------- launch -----------------------------------

extern "C" void kernel_launch(void* const* d_in, const int* in_sizes, int n_in,
                              void* d_out, int out_size, void* d_ws, size_t ws_size,
                              hipStream_t stream) {
  const int*   ids  = (const int*)d_in[0];
  const int*   mask = (const int*)d_in[1];
  const float* emb  = (const float*)d_in[2];
  const float* wi   = (const float*)d_in[3];
  const float* wh   = (const float*)d_in[4];
  const float* binp = (const float*)d_in[5];
  const float* bhid = (const float*)d_in[6];
  const float* lw   = (const float*)d_in[7];
  const float* lb   = (const float*)d_in[8];
  char* ws = (char*)d_ws;
  float* out = (float*)d_out;
  (void)in_sizes; (void)n_in; (void)out_size; (void)ws_size;

  hipMemsetAsync(ws, 0, ZERO_BYTES, stream);
  k_maxw<<<256, 256, 0, stream>>>(wi, wh, lw, (unsigned*)ws);
  k_sx<<<SEQ, 256, 0, stream>>>(ids, emb, (float*)(ws + OFF_SX));
  k_len<<<1, 64, 0, stream>>>(mask, (int*)(ws + OFF_LEN));
  k_wf<<<256, 256, 0, stream>>>(wi, wh, (const unsigned*)ws,
                                (v4i*)(ws + OFF_WIF), (v4i*)(ws + OFF_WHF));
  k_xf<<<4096, 256, 0, stream>>>(ids, emb, (const float*)(ws + OFF_SX),
                                 (v4i*)(ws + OFF_XF));
  k_main<<<NBLK, NTHR, 0, stream>>>(ws, binp, bhid, lw, lb, out);
}

// Round 4
// 2834.143 us; speedup vs baseline: 2.4130x; 2.4130x over previous
//
#include <hip/hip_runtime.h>
#include <cstdint>
#include <cstddef>

// ============================================================================
// LSTMClassifierQuantized: B=64, S=512, H=E=512, 4H=2048, per-tensor int8
// fake-quant on x_t/h/c/W per step. Sequential 512 steps, one grid barrier
// per step (global max|h|, max|c| scales force it).
//
// R4 design (vs R1 9.5us/step, R2 11.3, R3 13.3):
//  - NO cache-maintenance fences in steady state. h ring buffer of 32 slots
//    (one per step mod 32): producers write h via L2-BYPASS atomic stores
//    (land at coherence point); consumers use PLAIN CACHED loads — address
//    is fresh (never in L2) so the compulsory miss fetches coherent data
//    from L3 AND gets same-XCD L2 dedup. buffer_inv only every 32 steps,
//    right before a slot is reused (kills any stale clean line).
//  - hybrid partition: 4 row-groups x 16 col-groups (64 blk x 256 thr).
//    Block (rg,cg): rows [rg*16,+16), local cols 128 (4 gates x 32 units).
//    h read per block = 16x512 fp32 = 32 KB (4x less than R1).
//    bk->(rg,cg): rg=(bk&7)>>1, cg=((bk>>3)<<1)|(bk&1) so round-robin
//    XCD placement gives each XCD ONE rg (32 KB/XCD/step from L3).
//  - barrier: R1's proven single-line counter (tid0: atomicMax scales to
//    per-step fresh slots, vmcnt drain, atomicAdd cnt, spin).
//  - x int8 fragments prefetched to VGPRs during the spin; weights stay in
//    VGPRs whole kernel (128 VGPRs; 1 wave/SIMD, launch_bounds(256,1)).
// ============================================================================

typedef int v4i __attribute__((ext_vector_type(4)));

#define NB   64
#define SEQ  512
#define HID  512
#define G4   2048
#define NBLK 64
#define NTHR 256
#define HSLOTS 32

// workspace byte offsets
#define OFF_CNT     0             // u32 barrier counter
#define OFF_SLOT1   64            // u32[4]: wi, wh, lw abs-max bits
#define OFF_FREC    128           // u32[64] final capmax records
#define OFF_SLOTH   384           // u32[513] per-step max|h| (atomicMax)
#define OFF_SLOTC   2436          // u32[513] per-step max|c|
#define OFF_SX      4488          // f32[512] raw max|x_t|
#define OFF_LEN     6536          // i32[64]
#define OFF_HG      8192          // f32[32 slots][4 rg][16][512] ring
#define ZERO_BYTES  139264        // through hg slot 0
#define OFF_HLAST   4202496       // f32[64*512] row-major
#define OFF_WIF     4333568       // v4i[65536] frag-major int8 Wi (1 MB)
#define OFF_WHF     5382144       // v4i[65536]
#define OFF_XF      6430720       // v4i[512*4*8*64] frag-major int8 x (16 MB)
#define WS_NEED     23207936

#define ATOMIC_LD(p)    __hip_atomic_load((p), __ATOMIC_RELAXED, __HIP_MEMORY_SCOPE_AGENT)
#define ATOMIC_ST(p, v) __hip_atomic_store((p), (v), __ATOMIC_RELAXED, __HIP_MEMORY_SCOPE_AGENT)

__device__ __forceinline__ float sigm(float x) {
  return 1.0f / (1.0f + __expf(-x));
}

// magic-number round-to-nearest-even int8 pack (|x*inv| <= 127)
__device__ __forceinline__ int pack4q(float4 v, float inv) {
  union { float f; unsigned u; } a, b, c, d;
  a.f = __builtin_fmaf(v.x, inv, 12582912.0f);   // 1.5 * 2^23
  b.f = __builtin_fmaf(v.y, inv, 12582912.0f);
  c.f = __builtin_fmaf(v.z, inv, 12582912.0f);
  d.f = __builtin_fmaf(v.w, inv, 12582912.0f);
  return (int)((a.u & 0xffu) | ((b.u & 0xffu) << 8) |
               ((c.u & 0xffu) << 16) | ((d.u & 0xffu) << 24));
}

// exact-IEEE-division quantize pack (setup kernels)
__device__ __forceinline__ unsigned packdiv(const float* p, float s) {
  unsigned r = 0;
#pragma unroll
  for (int j = 0; j < 4; j++) {
    int n = (int)rintf(p[j] / s);
    r |= ((unsigned)n & 0xffu) << (8 * j);
  }
  return r;
}

// ------------------------------- setup kernels ------------------------------

__global__ void k_maxw(const float* __restrict__ wi, const float* __restrict__ wh,
                       const float* __restrict__ lw, unsigned* ws_u) {
  float m1 = 0.f, m2 = 0.f, m3 = 0.f;
  int stride = gridDim.x * blockDim.x;
  int t0 = blockIdx.x * blockDim.x + threadIdx.x;
  for (int i = t0; i < G4 * HID; i += stride) m1 = fmaxf(m1, fabsf(wi[i]));
  for (int i = t0; i < G4 * HID; i += stride) m2 = fmaxf(m2, fabsf(wh[i]));
  for (int i = t0; i < HID; i += stride)      m3 = fmaxf(m3, fabsf(lw[i]));
#pragma unroll
  for (int o = 32; o > 0; o >>= 1) {
    m1 = fmaxf(m1, __shfl_down(m1, o));
    m2 = fmaxf(m2, __shfl_down(m2, o));
    m3 = fmaxf(m3, __shfl_down(m3, o));
  }
  __shared__ float s1[4], s2[4], s3[4];
  int w = threadIdx.x >> 6, l = threadIdx.x & 63;
  if (l == 0) { s1[w] = m1; s2[w] = m2; s3[w] = m3; }
  __syncthreads();
  if (threadIdx.x == 0) {
    m1 = fmaxf(fmaxf(s1[0], s1[1]), fmaxf(s1[2], s1[3]));
    m2 = fmaxf(fmaxf(s2[0], s2[1]), fmaxf(s2[2], s2[3]));
    m3 = fmaxf(fmaxf(s3[0], s3[1]), fmaxf(s3[2], s3[3]));
    atomicMax(&ws_u[OFF_SLOT1 / 4 + 0], __float_as_uint(m1));
    atomicMax(&ws_u[OFF_SLOT1 / 4 + 1], __float_as_uint(m2));
    atomicMax(&ws_u[OFF_SLOT1 / 4 + 2], __float_as_uint(m3));
  }
}

__global__ void k_sx(const int* __restrict__ ids, const float* __restrict__ emb,
                     float* sx) {
  int t = blockIdx.x, tid = threadIdx.x;
  int row = tid >> 2, qu = tid & 3;
  const float* e = emb + (size_t)ids[row * SEQ + t] * HID + qu * 128;
  float m = 0.f;
  for (int i = 0; i < 128; i++) m = fmaxf(m, fabsf(e[i]));
#pragma unroll
  for (int o = 32; o > 0; o >>= 1) m = fmaxf(m, __shfl_down(m, o));
  __shared__ float sm[4];
  if ((tid & 63) == 0) sm[tid >> 6] = m;
  __syncthreads();
  if (tid == 0) sx[t] = fmaxf(fmaxf(sm[0], sm[1]), fmaxf(sm[2], sm[3]));
}

__global__ void k_len(const int* __restrict__ mask, int* len) {
  int b = threadIdx.x;
  int s = 0;
  for (int i = 0; i < SEQ; i++) s += mask[b * SEQ + i];
  len[b] = (s + SEQ - 1) & (SEQ - 1);   // (sum-1) mod 512, jnp wrap semantics
}

// Weight fragments: wf[cg(16)][n(8)][kb(8)][lane(64)] (B-operand, 16x16x64).
// Local col lcol = n*16 + (lane&15): gate g = lcol>>5, unit ul = lcol&31;
// global col = g*512 + cg*32 + ul.  k = kb*64 + (lane>>4)*16 + 0..15.
__global__ void k_wf(const float* __restrict__ wi, const float* __restrict__ wh,
                     const unsigned* ws_u, v4i* wif, v4i* whf) {
  int t = blockIdx.x * 256 + threadIdx.x;          // 0..65535
  int lane = t & 63, kb = (t >> 6) & 7, n = (t >> 9) & 7, cg = t >> 12;
  int cc = lane & 15, q = lane >> 4;
  int lcol = n * 16 + cc;
  int col = (lcol >> 5) * 512 + cg * 32 + (lcol & 31);
  int k0 = kb * 64 + q * 16;
  float si = fmaxf(__uint_as_float(ws_u[OFF_SLOT1 / 4 + 0]), 1e-8f) / 127.0f;
  float sh = fmaxf(__uint_as_float(ws_u[OFF_SLOT1 / 4 + 1]), 1e-8f) / 127.0f;
  float buf[16];
#pragma unroll
  for (int j = 0; j < 16; j++) buf[j] = wi[(size_t)col * 512 + k0 + j];
  v4i o;
  o[0] = (int)packdiv(buf + 0, si);  o[1] = (int)packdiv(buf + 4, si);
  o[2] = (int)packdiv(buf + 8, si);  o[3] = (int)packdiv(buf + 12, si);
  wif[t] = o;
#pragma unroll
  for (int j = 0; j < 16; j++) buf[j] = wh[(size_t)col * 512 + k0 + j];
  o[0] = (int)packdiv(buf + 0, sh);  o[1] = (int)packdiv(buf + 4, sh);
  o[2] = (int)packdiv(buf + 8, sh);  o[3] = (int)packdiv(buf + 12, sh);
  whf[t] = o;
}

// x fragments: xf[t(512)][rg(4)][kb(8)][lane(64)] (A-operand for M=16).
// Lane holds A[row = rg*16 + (lane&15)][k = kb*64 + (lane>>4)*16 + 0..15].
__global__ void k_xf(const int* __restrict__ ids, const float* __restrict__ emb,
                     const float* __restrict__ sx, v4i* xf) {
  int g = blockIdx.x * 256 + threadIdx.x;          // 0..1048575
  int lane = g & 63, kb = (g >> 6) & 7, rg = (g >> 9) & 3, t = g >> 11;
  int row = rg * 16 + (lane & 15);
  int k0 = kb * 64 + (lane >> 4) * 16;
  float s = fmaxf(sx[t], 1e-8f) / 127.0f;
  const float* e = emb + (size_t)ids[row * SEQ + t] * HID + k0;
  float buf[16];
#pragma unroll
  for (int j = 0; j < 16; j++) buf[j] = e[j];
  v4i o;
  o[0] = (int)packdiv(buf + 0, s);  o[1] = (int)packdiv(buf + 4, s);
  o[2] = (int)packdiv(buf + 8, s);  o[3] = (int)packdiv(buf + 12, s);
  xf[g] = o;
}

// ------------------------------ persistent kernel ---------------------------

__global__ __launch_bounds__(NTHR, 1) void k_main(
    char* ws, const float* __restrict__ b_inp, const float* __restrict__ b_hid,
    const float* __restrict__ lin_w, const float* __restrict__ lin_b,
    float* __restrict__ out) {
  const int tid  = threadIdx.x;
  const int bk   = blockIdx.x;
  const int lane = tid & 63;
  const int wv   = tid >> 6;               // 4 waves
  const int cc   = lane & 15, qq = lane >> 4;
  const int rg   = (bk & 7) >> 1;          // same rg for all blocks on an XCD
  const int cg   = ((bk >> 3) << 1) | (bk & 1);

  unsigned* cnt   = (unsigned*)(ws + OFF_CNT);
  unsigned* slot1 = (unsigned*)(ws + OFF_SLOT1);
  unsigned* frec  = (unsigned*)(ws + OFF_FREC);
  unsigned* sloth = (unsigned*)(ws + OFF_SLOTH);
  unsigned* slotc = (unsigned*)(ws + OFF_SLOTC);
  const float* sxr = (const float*)(ws + OFF_SX);
  const int* lens  = (const int*)(ws + OFF_LEN);
  float* hg    = (float*)(ws + OFF_HG);
  float* hlast = (float*)(ws + OFF_HLAST);
  const v4i* wifg = (const v4i*)(ws + OFF_WIF);
  const v4i* whfg = (const v4i*)(ws + OFF_WHF);
  const v4i* xfg  = (const v4i*)(ws + OFF_XF);

  __shared__ v4i hf[512];            // 8 KB int8 h A-fragments
  __shared__ v4i xl[512];            // 8 KB int8 x A-fragments
  __shared__ float gl[16][132];      // gates [row][lcol], padded
  __shared__ float redh[4], redc[4];

  // weight fragments -> VGPRs for the whole kernel (2 col-tiles per wave)
  const int n0 = wv * 2, n1 = n0 + 1;
  v4i wi0[8], wi1[8], wh0[8], wh1[8];
#pragma unroll
  for (int kb = 0; kb < 8; kb++) {
    wi0[kb] = wifg[((cg * 8 + n0) * 8 + kb) * 64 + lane];
    wi1[kb] = wifg[((cg * 8 + n1) * 8 + kb) * 64 + lane];
    wh0[kb] = whfg[((cg * 8 + n0) * 8 + kb) * 64 + lane];
    wh1[kb] = whfg[((cg * 8 + n1) * 8 + kb) * 64 + lane];
  }
  const int lcol0 = n0 * 16 + cc, lcol1 = n1 * 16 + cc;
  const int col0 = (lcol0 >> 5) * 512 + cg * 32 + (lcol0 & 31);
  const int col1 = (lcol1 >> 5) * 512 + cg * 32 + (lcol1 & 31);
  const float bi0 = b_inp[col0], bh0 = b_hid[col0];
  const float bi1 = b_inp[col1], bh1 = b_hid[col1];
  const float swi = fmaxf(__uint_as_float(slot1[0]), 1e-8f) / 127.0f;
  const float swh = fmaxf(__uint_as_float(slot1[1]), 1e-8f) / 127.0f;

  // h-stage mapping: thread loads row lr2, units [useg*32, +32)
  const int lr2 = tid >> 4, useg = tid & 15;
  const int hidx0 = (useg >> 1) * 64 + ((useg * 2) & 3) * 16 + lr2;
  // cell mapping: thread owns (row lr, local units ul0, ul0+1)
  const int lr = tid >> 4, ul0 = (tid & 15) * 2;
  const int grow = rg * 16 + lr;           // global row
  const int gu = cg * 32 + ul0;            // global unit (8B-aligned pair)
  const int mylen = lens[grow];
  float c0 = 0.0f, c1 = 0.0f, capmax = 0.0f;

  // x prefetch for t=0 (2 chunks/thread)
  v4i xa0 = xfg[(size_t)rg * 512 + 2 * tid];
  v4i xa1 = xfg[(size_t)rg * 512 + 2 * tid + 1];

  for (int t = 0; t < SEQ; ++t) {
    // ---- grid barrier (R1-style single-line counter) ----
    if (t) {
      if (tid == 0) {
        unsigned tgt = (unsigned)NBLK * (unsigned)t;
        while (ATOMIC_LD(cnt) < tgt) __builtin_amdgcn_s_sleep(1);
      }
      __syncthreads();
      // slot (t & 31) is about to be re-read; drop any line cached 32 steps
      // ago. Only every 32 steps — amortized.
      if ((t & (HSLOTS - 1)) == 0)
        __builtin_amdgcn_fence(__ATOMIC_ACQUIRE, "agent");
    }

    // scales: per-step fresh addresses -> plain cached loads are coherent
    const float th   = fmaxf(__uint_as_float(sloth[t]), 1e-8f);
    const float invh = 127.0f / th;
    const float tc   = fmaxf(__uint_as_float(slotc[t]), 1e-8f);
    const float scq  = tc / 127.0f;
    const float invc = 127.0f / tc;
    const float fx = (fmaxf(sxr[t], 1e-8f) / 127.0f) * swi;
    const float fh = (th / 127.0f) * swh;

    // ---- h: plain cached loads from fresh ring slot -> pack -> LDS ----
    {
      const float4* hp = (const float4*)(hg +
          ((size_t)(t & (HSLOTS - 1)) * 4 + rg) * (16 * 512) +
          lr2 * 512 + useg * 32);
      float4 f0 = hp[0], f1 = hp[1], f2 = hp[2], f3 = hp[3];
      float4 f4 = hp[4], f5 = hp[5], f6 = hp[6], f7 = hp[7];
      v4i pk0, pk1;
      pk0[0] = pack4q(f0, invh); pk0[1] = pack4q(f1, invh);
      pk0[2] = pack4q(f2, invh); pk0[3] = pack4q(f3, invh);
      pk1[0] = pack4q(f4, invh); pk1[1] = pack4q(f5, invh);
      pk1[2] = pack4q(f6, invh); pk1[3] = pack4q(f7, invh);
      hf[hidx0]      = pk0;
      hf[hidx0 + 16] = pk1;
      xl[2 * tid]     = xa0;
      xl[2 * tid + 1] = xa1;
    }
    __syncthreads();   // (A) hf + xl ready

    // ---- GEMM: exact int8 MFMA; A shared across both col-tiles ----
    v4i ax0 = {0,0,0,0}, ax1 = {0,0,0,0}, ah0 = {0,0,0,0}, ah1 = {0,0,0,0};
#pragma unroll
    for (int kb = 0; kb < 8; kb++) {
      v4i a_x = xl[kb * 64 + lane];
      v4i a_h = hf[kb * 64 + lane];
      ax0 = __builtin_amdgcn_mfma_i32_16x16x64_i8(a_x, wi0[kb], ax0, 0, 0, 0);
      ah0 = __builtin_amdgcn_mfma_i32_16x16x64_i8(a_h, wh0[kb], ah0, 0, 0, 0);
      ax1 = __builtin_amdgcn_mfma_i32_16x16x64_i8(a_x, wi1[kb], ax1, 0, 0, 0);
      ah1 = __builtin_amdgcn_mfma_i32_16x16x64_i8(a_h, wh1[kb], ah1, 0, 0, 0);
    }
    // epilogue: mirror np order ((x@WiT + b_inp) + h@WhT) + b_hid
#pragma unroll
    for (int r = 0; r < 4; r++) {
      int lrow = qq * 4 + r;
      gl[lrow][lcol0] = (((float)ax0[r] * fx + bi0) + (float)ah0[r] * fh) + bh0;
      gl[lrow][lcol1] = (((float)ax1[r] * fx + bi1) + (float)ah1[r] * fh) + bh1;
    }
    __syncthreads();   // (B) gates ready

    // prefetch x(t+1) now — overlaps cell phase and the barrier spin
    if (t + 1 < SEQ) {
      const v4i* xn = xfg + ((size_t)(t + 1) * 4 + rg) * 512;
      xa0 = xn[2 * tid];
      xa1 = xn[2 * tid + 1];
    }

    // ---- elementwise LSTM cell (2 cells/thread, c in registers) ----
    float i0 = sigm(gl[lr][ul0]);
    float i1 = sigm(gl[lr][ul0 + 1]);
    float f0 = sigm(gl[lr][32 + ul0]);
    float f1 = sigm(gl[lr][32 + ul0 + 1]);
    float g0 = tanhf(gl[lr][64 + ul0]);
    float g1 = tanhf(gl[lr][64 + ul0 + 1]);
    float o0 = sigm(gl[lr][96 + ul0]);
    float o1 = sigm(gl[lr][96 + ul0 + 1]);
    float cq0 = rintf(c0 * invc) * scq;
    float cq1 = rintf(c1 * invc) * scq;
    float cn0 = f0 * cq0 + i0 * g0;
    float cn1 = f1 * cq1 + i1 * g1;
    float hn0 = o0 * tanhf(cn0);
    float hn1 = o1 * tanhf(cn1);
    c0 = cn0; c1 = cn1;

    // publish h: L2-bypass store into FRESH ring slot (coherence point)
    union { float f[2]; unsigned long long u; } hu;
    hu.f[0] = hn0; hu.f[1] = hn1;
    ATOMIC_ST((unsigned long long*)(hg +
        ((size_t)((t + 1) & (HSLOTS - 1)) * 4 + rg) * (16 * 512) +
        lr * 512 + gu), hu.u);
    if (t == mylen) {
      ATOMIC_ST((unsigned long long*)(hlast + (size_t)grow * 512 + gu), hu.u);
      capmax = fmaxf(capmax, fmaxf(fabsf(hn0), fabsf(hn1)));
    }

    // block abs-max of new h and c
    float mhv = fmaxf(fabsf(hn0), fabsf(hn1));
    float mcv = fmaxf(fabsf(cn0), fabsf(cn1));
#pragma unroll
    for (int o = 32; o > 0; o >>= 1) {
      mhv = fmaxf(mhv, __shfl_down(mhv, o));
      mcv = fmaxf(mcv, __shfl_down(mcv, o));
    }
    if (lane == 0) { redh[wv] = mhv; redc[wv] = mcv; }
    __syncthreads();   // (C) h stores drained (vmcnt0 at barrier), reds ready

    if (tid == 0) {
      float MH = fmaxf(fmaxf(redh[0], redh[1]), fmaxf(redh[2], redh[3]));
      float MC = fmaxf(fmaxf(redc[0], redc[1]), fmaxf(redc[2], redc[3]));
      atomicMax(&sloth[t + 1], __float_as_uint(MH));
      atomicMax(&slotc[t + 1], __float_as_uint(MC));
      asm volatile("s_waitcnt vmcnt(0)" ::: "memory");  // scales visible first
      __hip_atomic_fetch_add(cnt, 1u, __ATOMIC_RELAXED, __HIP_MEMORY_SCOPE_AGENT);
    }
  }

  // ---- final round: publish capture max, block 0 computes logits ----
#pragma unroll
  for (int o = 32; o > 0; o >>= 1)
    capmax = fmaxf(capmax, __shfl_down(capmax, o));
  if (lane == 0) redh[wv] = capmax;
  __syncthreads();
  if (tid == 0) {
    float CM = fmaxf(fmaxf(redh[0], redh[1]), fmaxf(redh[2], redh[3]));
    ATOMIC_ST(&frec[bk], __float_as_uint(CM));
    asm volatile("s_waitcnt vmcnt(0)" ::: "memory");   // frec + hlast visible
    __hip_atomic_fetch_add(cnt, 1u, __ATOMIC_RELAXED, __HIP_MEMORY_SCOPE_AGENT);
  }
  if (bk != 0) return;

  if (tid == 0) {
    unsigned tgt = (unsigned)NBLK * (unsigned)(SEQ + 1);
    while (ATOMIC_LD(cnt) < tgt) __builtin_amdgcn_s_sleep(1);
  }
  __syncthreads();

  {
    // global capture max from the 64 block records
    float cm = 0.0f;
    if (wv == 0) {
      float v = __uint_as_float(ATOMIC_LD(&frec[lane]));
#pragma unroll
      for (int o = 32; o > 0; o >>= 1) v = fmaxf(v, __shfl_down(v, o));
      if (lane == 0) { redh[0] = v; }
    }
    __syncthreads();
    cm = redh[0];

    float tHL = fmaxf(cm, 1e-8f);
    float sHL = tHL / 127.0f, invHL = 127.0f / tHL;
    float tLW = fmaxf(__uint_as_float(slot1[2]), 1e-8f);
    float sLW = tLW / 127.0f, invLW = 127.0f / tLW;
    int b = tid >> 2, seg = tid & 3;
    const unsigned long long* hp =
        (const unsigned long long*)(hlast + (size_t)b * 512 + seg * 128);
    float acc = 0.0f;
    for (int j = 0; j < 64; ++j) {
      union { unsigned long long u; float f[2]; } d;
      d.u = ATOMIC_LD(hp + j);
      float hq0 = rintf(d.f[0] * invHL) * sHL;
      float wq0 = rintf(lin_w[seg * 128 + 2 * j] * invLW) * sLW;
      acc += hq0 * wq0;
      float hq1 = rintf(d.f[1] * invHL) * sHL;
      float wq1 = rintf(lin_w[seg * 128 + 2 * j + 1] * invLW) * sLW;
      acc += hq1 * wq1;
    }
    float* fl = &gl[0][0];
    fl[tid] = acc;                 // tid = b*4 + seg
    __syncthreads();
    if (tid < 64) {
      float s = fl[tid * 4] + fl[tid * 4 + 1] + fl[tid * 4 + 2] + fl[tid * 4 + 3];
      out[tid] = s + lin_b[0];
    }
  }
}

// --------------------------------- launch -----------------------------------

extern "C" void kernel_launch(void* const* d_in, const int* in_sizes, int n_in,
                              void* d_out, int out_size, void* d_ws, size_t ws_size,
                              hipStream_t stream) {
  const int*   ids  = (const int*)d_in[0];
  const int*   mask = (const int*)d_in[1];
  const float* emb  = (const float*)d_in[2];
  const float* wi   = (const float*)d_in[3];
  const float* wh   = (const float*)d_in[4];
  const float* binp = (const float*)d_in[5];
  const float* bhid = (const float*)d_in[6];
  const float* lw   = (const float*)d_in[7];
  const float* lb   = (const float*)d_in[8];
  char* ws = (char*)d_ws;
  float* out = (float*)d_out;
  (void)in_sizes; (void)n_in; (void)out_size; (void)ws_size;

  hipMemsetAsync(ws, 0, ZERO_BYTES, stream);
  k_maxw<<<256, 256, 0, stream>>>(wi, wh, lw, (unsigned*)ws);
  k_sx<<<SEQ, 256, 0, stream>>>(ids, emb, (float*)(ws + OFF_SX));
  k_len<<<1, 64, 0, stream>>>(mask, (int*)(ws + OFF_LEN));
  k_wf<<<256, 256, 0, stream>>>(wi, wh, (const unsigned*)ws,
                                (v4i*)(ws + OFF_WIF), (v4i*)(ws + OFF_WHF));
  k_xf<<<4096, 256, 0, stream>>>(ids, emb, (const float*)(ws + OFF_SX),
                                 (v4i*)(ws + OFF_XF));
  k_main<<<NBLK, NTHR, 0, stream>>>(ws, binp, bhid, lw, lb, out);
}